// Round 4
// baseline (714.051 us; speedup 1.0000x reference)
//
#include <hip/hip_runtime.h>
#include <stdint.h>

#define Lc 96
#define Hc 8
#define Ec 64
#define EHc 128
#define AP 68            // A_pk pitch (dwords): 4c+8g start banks, balanced
#define HP 132           // H_pk pitch (dwords)
#define JS (Hc * Ec * 2) // out stride per j = 1024 floats

typedef __attribute__((ext_vector_type(8))) short short8;
typedef __attribute__((ext_vector_type(4))) float floatx4;

union FragU { uint32_t u[4]; short8 v; };
union FragH { uint16_t h[8]; short8 v; };

// tanh(x) = 1 - 2/(e^{2x}+1)
__device__ __forceinline__ float fast_tanh(float x) {
    const float e = __builtin_amdgcn_exp2f(x * 2.8853900817779268f);
    return 1.0f - 2.0f * __builtin_amdgcn_rcpf(e + 1.0f);
}

// fp32 -> (hi bf16 in low16) | (lo bf16 in high16); hi+lo ~2^-17 rel.
__device__ __forceinline__ uint32_t pack_hl(float v) {
    const uint32_t uv = __float_as_uint(v);
    const float hf = __uint_as_float(uv & 0xffff0000u);
    const uint32_t lo = __float_as_uint(v - hf) >> 16;
    return (uv >> 16) | (lo << 16);
}

// De-interleave 8 packed (hi|lo) u32 -> hi-frag + lo-frag via v_perm_b32.
__device__ __forceinline__ void unpack2(const uint32_t* p, short8& hi, short8& lo) {
    const uint4 d0 = *(const uint4*)p;
    const uint4 d1 = *(const uint4*)(p + 4);
    FragU H, L;
    H.u[0] = __builtin_amdgcn_perm(d0.y, d0.x, 0x05040100u);
    H.u[1] = __builtin_amdgcn_perm(d0.w, d0.z, 0x05040100u);
    H.u[2] = __builtin_amdgcn_perm(d1.y, d1.x, 0x05040100u);
    H.u[3] = __builtin_amdgcn_perm(d1.w, d1.z, 0x05040100u);
    L.u[0] = __builtin_amdgcn_perm(d0.y, d0.x, 0x07060302u);
    L.u[1] = __builtin_amdgcn_perm(d0.w, d0.z, 0x07060302u);
    L.u[2] = __builtin_amdgcn_perm(d1.y, d1.x, 0x07060302u);
    L.u[3] = __builtin_amdgcn_perm(d1.w, d1.z, 0x07060302u);
    hi = H.v; lo = L.v;
}

// 768 blocks x 128 threads (2 waves). Each block: 16 rows of one trajectory,
// ONE direction (fwd or bwd) -- the two sweeps are independent chains.
// blockIdx -> (pair-rank i, fwd/bwd, rowgroup): both jobs of rank i have
// length 95-i, longest first (LPT); with 4 blocks/CU co-resident all 768
// blocks are resident at once, so the machine is fully balanced.
// Wave w: L1 hidden cols [64w,64w+64) (4 tiles), L2 cols [32w,32w+32) (2 tiles).
// Weights register-resident as bf16 hi/lo B-frags (128 VGPRs/wave).
__global__ __launch_bounds__(128, 2)
void ode_mfma_kernel(const float* __restrict__ x, const float* __restrict__ ts,
                     const float* __restrict__ W1, const float* __restrict__ b1,
                     const float* __restrict__ W2, const float* __restrict__ b2,
                     float* __restrict__ out)
{
    __shared__ uint32_t A_pk[16 * AP];   // arg, [row][e] packed hi|lo
    __shared__ uint32_t H_pk[16 * HP];   // hidden, [row][n] packed hi|lo
    __shared__ float    tss[Lc];

    const int tid  = threadIdx.x;
    const int w    = tid >> 6;      // wave 0..1
    const int lane = tid & 63;
    const int g    = lane >> 4;     // quad 0..3
    const int c    = lane & 15;

    if (tid < Lc) tss[tid] = ts[tid];

    // ---- schedule ----
    const int  i    = blockIdx.x >> 3;   // pair-rank 0..95, work = 95-i
    const int  k8   = blockIdx.x & 7;
    const bool fwd  = (k8 < 4);
    const int  rg   = k8 & 3;            // rowgroup 0..3 (16 rows each)
    const int  t    = fwd ? i : (Lc - 1 - i);
    const int  nsteps = (Lc - 1) - i;    // fwd: 95-t ; bwd: t

    // ---- register-resident weight B-frags: B[k = ks*32+g*8+j][n] ----
    short8 w1h[4][2], w1l[4][2];         // [ct][ks], n = 64w+16ct+c
    short8 w2h[2][4], w2l[2][4];         // [ct2][ks], n = 32w+16ct2+c
#pragma unroll
    for (int ct = 0; ct < 4; ++ct)
#pragma unroll
        for (int ks = 0; ks < 2; ++ks) {
            FragH fh, fl;
#pragma unroll
            for (int j = 0; j < 8; ++j) {
                const int k = ks * 32 + g * 8 + j;
                const int n = 64 * w + 16 * ct + c;
                const float v = W1[k * EHc + n];
                const uint32_t uv = __float_as_uint(v);
                const float hf = __uint_as_float(uv & 0xffff0000u);
                fh.h[j] = (uint16_t)(uv >> 16);
                fl.h[j] = (uint16_t)(__float_as_uint(v - hf) >> 16);
            }
            w1h[ct][ks] = fh.v; w1l[ct][ks] = fl.v;
        }
#pragma unroll
    for (int ct2 = 0; ct2 < 2; ++ct2)
#pragma unroll
        for (int ks = 0; ks < 4; ++ks) {
            FragH fh, fl;
#pragma unroll
            for (int j = 0; j < 8; ++j) {
                const int k = ks * 32 + g * 8 + j;
                const int n = 32 * w + 16 * ct2 + c;
                const float v = W2[k * Ec + n];
                const uint32_t uv = __float_as_uint(v);
                const float hf = __uint_as_float(uv & 0xffff0000u);
                fh.h[j] = (uint16_t)(uv >> 16);
                fl.h[j] = (uint16_t)(__float_as_uint(v - hf) >> 16);
            }
            w2h[ct2][ks] = fh.v; w2l[ct2][ks] = fl.v;
        }

    float b1v[4], b2v[2];
#pragma unroll
    for (int ct = 0; ct < 4; ++ct) b1v[ct] = b1[64 * w + 16 * ct + c];
#pragma unroll
    for (int ct2 = 0; ct2 < 2; ++ct2) b2v[ct2] = b2[32 * w + 16 * ct2 + c];

    // ---- state: lane holds rows g*4+reg, cols {32w+c, 32w+16+c} ----
    const int col0 = 32 * w + c;
    float2 y0_[4], y_[4];
    size_t ob_[4];
#pragma unroll
    for (int reg = 0; reg < 4; ++reg) {
        const int row  = g * 4 + reg;        // 0..15 within block
        const int grow = rg * 16 + row;      // 0..63 within trajectory
        const int bb   = grow >> 3;
        const int hh   = grow & 7;
        const float* xr = x + ((bb * Lc + t) * Hc + hh) * Ec;
        float2 v0; v0.x = xr[col0]; v0.y = xr[col0 + 16];
        y0_[reg] = v0; y_[reg] = v0;
        ob_[reg] = (size_t)(bb * Lc + t) * (Lc * JS) + hh * (Ec * 2) + col0 * 2;
        if (fwd) {  // j = t output (y0, y0) written once, by the fwd block
            float2 o0; o0.x = v0.x; o0.y = v0.x;
            float2 o1; o1.x = v0.y; o1.y = v0.y;
            *(float2*)(out + ob_[reg] + (size_t)t * JS)      = o0;
            *(float2*)(out + ob_[reg] + (size_t)t * JS + 32) = o1;
        }
        A_pk[row * AP + col0]      = pack_hl(v0.x);
        A_pk[row * AP + col0 + 16] = pack_hl(v0.y);
    }
    __syncthreads();

    // f(A_pk) -> kk[reg] = {col0, col0+16} outputs (C-layout rows g*4+reg).
    // Entry: A_pk valid+synced. One internal barrier (H handoff).
    auto evalf = [&](float2* kk) {
        short8 ahi[2], alo[2];
#pragma unroll
        for (int ks = 0; ks < 2; ++ks)
            unpack2(A_pk + c * AP + ks * 32 + g * 8, ahi[ks], alo[ks]);
        floatx4 p[4];
#pragma unroll
        for (int ct = 0; ct < 4; ++ct) {
            floatx4 acc = {b1v[ct], b1v[ct], b1v[ct], b1v[ct]};
#pragma unroll
            for (int ks = 0; ks < 2; ++ks) {
                acc = __builtin_amdgcn_mfma_f32_16x16x32_bf16(ahi[ks], w1h[ct][ks], acc, 0, 0, 0);
                acc = __builtin_amdgcn_mfma_f32_16x16x32_bf16(alo[ks], w1h[ct][ks], acc, 0, 0, 0);
                acc = __builtin_amdgcn_mfma_f32_16x16x32_bf16(ahi[ks], w1l[ct][ks], acc, 0, 0, 0);
            }
            p[ct] = acc;
        }
#pragma unroll
        for (int ct = 0; ct < 4; ++ct)
#pragma unroll
            for (int reg = 0; reg < 4; ++reg)
                H_pk[(g * 4 + reg) * HP + 64 * w + 16 * ct + c] = pack_hl(fast_tanh(p[ct][reg]));
        __syncthreads();
        floatx4 o0 = {b2v[0], b2v[0], b2v[0], b2v[0]};
        floatx4 o1 = {b2v[1], b2v[1], b2v[1], b2v[1]};
#pragma unroll
        for (int ks = 0; ks < 4; ++ks) {
            short8 hhi, hlo;
            unpack2(H_pk + c * HP + ks * 32 + g * 8, hhi, hlo);
            o0 = __builtin_amdgcn_mfma_f32_16x16x32_bf16(hhi, w2h[0][ks], o0, 0, 0, 0);
            o0 = __builtin_amdgcn_mfma_f32_16x16x32_bf16(hlo, w2h[0][ks], o0, 0, 0, 0);
            o0 = __builtin_amdgcn_mfma_f32_16x16x32_bf16(hhi, w2l[0][ks], o0, 0, 0, 0);
            o1 = __builtin_amdgcn_mfma_f32_16x16x32_bf16(hhi, w2h[1][ks], o1, 0, 0, 0);
            o1 = __builtin_amdgcn_mfma_f32_16x16x32_bf16(hlo, w2h[1][ks], o1, 0, 0, 0);
            o1 = __builtin_amdgcn_mfma_f32_16x16x32_bf16(hhi, w2l[1][ks], o1, 0, 0, 0);
        }
#pragma unroll
        for (int reg = 0; reg < 4; ++reg) { kk[reg].x = o0[reg]; kk[reg].y = o1[reg]; }
    };

    auto putA = [&](const float2* a) {
#pragma unroll
        for (int reg = 0; reg < 4; ++reg) {
            const int row = g * 4 + reg;
            A_pk[row * AP + col0]      = pack_hl(a[reg].x);
            A_pk[row * AP + col0 + 16] = pack_hl(a[reg].y);
        }
        __syncthreads();
    };

    for (int v = 0; v < nsteps; ++v) {
        const int s = fwd ? (t + v) : (t - v);
        const int jo = fwd ? (s + 1) : (s - 1);
        const float dt = tss[jo] - tss[s];

        float2 k1[4], k2[4], k3[4], k4[4], a[4];
        evalf(k1);
#pragma unroll
        for (int reg = 0; reg < 4; ++reg) {
            const float cdt = dt * (1.0f / 3.0f);
            a[reg].x = fmaf(cdt, k1[reg].x, y_[reg].x);
            a[reg].y = fmaf(cdt, k1[reg].y, y_[reg].y);
        }
        putA(a);
        evalf(k2);
#pragma unroll
        for (int reg = 0; reg < 4; ++reg) {
            a[reg].x = y_[reg].x + dt * (k2[reg].x - (1.0f / 3.0f) * k1[reg].x);
            a[reg].y = y_[reg].y + dt * (k2[reg].y - (1.0f / 3.0f) * k1[reg].y);
        }
        putA(a);
        evalf(k3);
#pragma unroll
        for (int reg = 0; reg < 4; ++reg) {
            a[reg].x = y_[reg].x + dt * (k1[reg].x - k2[reg].x + k3[reg].x);
            a[reg].y = y_[reg].y + dt * (k1[reg].y - k2[reg].y + k3[reg].y);
        }
        putA(a);
        evalf(k4);
#pragma unroll
        for (int reg = 0; reg < 4; ++reg) {
            y_[reg].x += dt * (k1[reg].x + 3.0f * (k2[reg].x + k3[reg].x) + k4[reg].x) * 0.125f;
            y_[reg].y += dt * (k1[reg].y + 3.0f * (k2[reg].y + k3[reg].y) + k4[reg].y) * 0.125f;
            float2 o0; o0.x = y0_[reg].x; o0.y = y_[reg].x;
            float2 o1; o1.x = y0_[reg].y; o1.y = y_[reg].y;
            *(float2*)(out + ob_[reg] + (size_t)jo * JS)      = o0;
            *(float2*)(out + ob_[reg] + (size_t)jo * JS + 32) = o1;
            a[reg] = y_[reg];
        }
        putA(a);
    }
}

extern "C" void kernel_launch(void* const* d_in, const int* in_sizes, int n_in,
                              void* d_out, int out_size, void* d_ws, size_t ws_size,
                              hipStream_t stream) {
    const float* x  = (const float*)d_in[0];
    const float* ts = (const float*)d_in[1];
    const float* W1 = (const float*)d_in[2];
    const float* b1 = (const float*)d_in[3];
    const float* W2 = (const float*)d_in[4];
    const float* b2 = (const float*)d_in[5];
    float* out = (float*)d_out;

    dim3 grid(768);    // 96 pair-ranks x (4 fwd + 4 bwd rowgroups), LPT order
    dim3 block(128);
    ode_mfma_kernel<<<grid, block, 0, stream>>>(x, ts, W1, b1, W2, b2, out);
}